// Round 7
// baseline (425.644 us; speedup 1.0000x reference)
//
#include <hip/hip_runtime.h>
#include <stdint.h>

#define NN 8192
#define DD 256

typedef __attribute__((ext_vector_type(8))) short short8;
typedef __attribute__((ext_vector_type(4))) float f32x4;

typedef const uint32_t __attribute__((address_space(1)))* gbl_ptr_t;
typedef uint32_t __attribute__((address_space(3)))* lds_ptr_t;

__device__ __forceinline__ void gl_lds16(const void* g, const void* l) {
    __builtin_amdgcn_global_load_lds((gbl_ptr_t)(uintptr_t)g,
                                     (lds_ptr_t)(uintptr_t)l, 16, 0, 0);
}

__device__ __forceinline__ unsigned short f32_to_bf16(float f) {
    uint32_t u = __float_as_uint(f);
    u += 0x7fff + ((u >> 16) & 1);   // RNE
    return (unsigned short)(u >> 16);
}
__device__ __forceinline__ float bf16_to_f32(unsigned short h) {
    return __uint_as_float(((uint32_t)h) << 16);
}

// ---------------------------------------------------------------------------
// prep: hi/lo bf16 split stored PRE-SWIZZLED (rule #21: linear LDS dest +
// inverse-swizzled global source + XOR on ds_read), sq[r], denom[r]=0.
// ---------------------------------------------------------------------------
__global__ void prep_kernel(const float* __restrict__ x,
                            unsigned short* __restrict__ hi,
                            unsigned short* __restrict__ lo,
                            float* __restrict__ sq,
                            float* __restrict__ denom) {
    const int r = blockIdx.x;
    const int t = threadIdx.x;                 // 0..255 = column
    float v = x[(size_t)r * DD + t];
    unsigned short h = f32_to_bf16(v);
    unsigned short l = f32_to_bf16(v - bf16_to_f32(h));
    int csw = (t & ~63) | ((((t >> 3) & 7) ^ (r & 7)) << 3) | (t & 7);
    hi[(size_t)r * DD + csw] = h;
    lo[(size_t)r * DD + csw] = l;

    float s = v * v;
    #pragma unroll
    for (int m = 32; m >= 1; m >>= 1) s += __shfl_xor(s, m, 64);
    __shared__ float ws[4];
    if ((t & 63) == 0) ws[t >> 6] = s;
    __syncthreads();
    if (t == 0) {
        sq[r] = ws[0] + ws[1] + ws[2] + ws[3];
        denom[r] = 0.0f;
    }
}

// ---------------------------------------------------------------------------
// Shared K-loop macro-equivalent: both kernels below run the identical
// 128x128-tile, 4-wave, mfma_f32_16x16x32_bf16 (hh+hl+lh) pipeline with
// global_load_lds staging (R3 structure — m151: gl_lds wins at 128^2).
// acc[fm][fn][r] then holds dot(x_row, x_col) in fp32.
// ---------------------------------------------------------------------------
#define DIST_KLOOP()                                                          \
    for (int kt = 0; kt < 4; ++kt) {                                          \
        _Pragma("unroll")                                                     \
        for (int c = 0; c < 4; ++c) {                                         \
            int lin  = c * 256 + tid;                                         \
            int row  = lin >> 3;                                              \
            int col8 = lin & 7;                                               \
            size_t goffA = (size_t)(row0 + row) * DD + kt * 64 + col8 * 8;    \
            size_t goffB = (size_t)(col0 + row) * DD + kt * 64 + col8 * 8;    \
            size_t lbyte = (size_t)(c * 256 + wid * 64) * 16;                 \
            gl_lds16(hi + goffA, (const char*)ldsAhi + lbyte);                \
            gl_lds16(lo + goffA, (const char*)ldsAlo + lbyte);                \
            gl_lds16(hi + goffB, (const char*)ldsBhi + lbyte);                \
            gl_lds16(lo + goffB, (const char*)ldsBlo + lbyte);                \
        }                                                                     \
        __syncthreads();                                                      \
        _Pragma("unroll")                                                     \
        for (int ks = 0; ks < 2; ++ks) {                                      \
            short8 ah[4], al[4], bh[4], bl[4];                                \
            _Pragma("unroll")                                                 \
            for (int fm = 0; fm < 4; ++fm) {                                  \
                int row = wm * 64 + fm * 16 + l15;                            \
                int cb  = (ks * 64 + lk * 16) ^ ((row & 7) << 4);             \
                int off = row * 64 + (cb >> 1);                               \
                ah[fm] = *(const short8*)(ldsAhi + off);                      \
                al[fm] = *(const short8*)(ldsAlo + off);                      \
            }                                                                 \
            _Pragma("unroll")                                                 \
            for (int fn = 0; fn < 4; ++fn) {                                  \
                int row = wn * 64 + fn * 16 + l15;                            \
                int cb  = (ks * 64 + lk * 16) ^ ((row & 7) << 4);             \
                int off = row * 64 + (cb >> 1);                               \
                bh[fn] = *(const short8*)(ldsBhi + off);                      \
                bl[fn] = *(const short8*)(ldsBlo + off);                      \
            }                                                                 \
            _Pragma("unroll")                                                 \
            for (int fm = 0; fm < 4; ++fm)                                    \
                _Pragma("unroll")                                             \
                for (int fn = 0; fn < 4; ++fn) {                              \
                    acc[fm][fn] = __builtin_amdgcn_mfma_f32_16x16x32_bf16(    \
                        ah[fm], bh[fn], acc[fm][fn], 0, 0, 0);                \
                    acc[fm][fn] = __builtin_amdgcn_mfma_f32_16x16x32_bf16(    \
                        ah[fm], bl[fn], acc[fm][fn], 0, 0, 0);                \
                    acc[fm][fn] = __builtin_amdgcn_mfma_f32_16x16x32_bf16(    \
                        al[fm], bh[fn], acc[fm][fn], 0, 0, 0);                \
                }                                                             \
        }                                                                     \
        __syncthreads();                                                      \
    }

#define DIST_PROLOG()                                                         \
    const int tid  = threadIdx.x;                                             \
    const int lane = tid & 63;                                                \
    const int wid  = tid >> 6;                                                \
    const int wm = wid >> 1, wn = wid & 1;                                    \
    const int l15 = lane & 15, lk = lane >> 4;                                \
    int t = blockIdx.x, bi = 0;                                               \
    while (t >= 64 - bi) { t -= 64 - bi; ++bi; }                              \
    const int bj = bi + t;                                                    \
    const int row0 = bi * 128;                                                \
    const int col0 = bj * 128;                                                \
    const bool offdiag = (bj > bi);                                           \
    f32x4 acc[4][4];                                                          \
    _Pragma("unroll")                                                         \
    for (int a = 0; a < 4; ++a)                                               \
        _Pragma("unroll")                                                     \
        for (int b = 0; b < 4; ++b) acc[a][b] = (f32x4){0.f, 0.f, 0.f, 0.f};  \
    float rsq[4][4], csq[4];                                                  \
    _Pragma("unroll")                                                         \
    for (int fm = 0; fm < 4; ++fm)                                            \
        _Pragma("unroll")                                                     \
        for (int r = 0; r < 4; ++r)                                           \
            rsq[fm][r] = sq[row0 + wm * 64 + fm * 16 + lk * 4 + r];           \
    _Pragma("unroll")                                                         \
    for (int fn = 0; fn < 4; ++fn)                                            \
        csq[fn] = sq[col0 + wn * 64 + fn * 16 + l15];

// ---------------------------------------------------------------------------
// Pass 1: denom sums only.  No global stores, no LDS transpose — this
// kernel's duration isolates the K-loop cost.
// ---------------------------------------------------------------------------
__launch_bounds__(256, 2)
__global__ void sum_kernel(const unsigned short* __restrict__ hi,
                           const unsigned short* __restrict__ lo,
                           const float* __restrict__ sq,
                           float* __restrict__ denom) {
    __shared__ __align__(16) unsigned short lds[4 * 128 * 64];  // 64 KB
    unsigned short* ldsAhi = lds;
    unsigned short* ldsAlo = lds + 8192;
    unsigned short* ldsBhi = lds + 16384;
    unsigned short* ldsBlo = lds + 24576;

    DIST_PROLOG()
    DIST_KLOOP()

    float rp[4][4], cp[4];
    #pragma unroll
    for (int a = 0; a < 4; ++a) {
        cp[a] = 0.f;
        #pragma unroll
        for (int b = 0; b < 4; ++b) rp[a][b] = 0.f;
    }
    #pragma unroll
    for (int fm = 0; fm < 4; ++fm)
        #pragma unroll
        for (int fn = 0; fn < 4; ++fn)
            #pragma unroll
            for (int r = 0; r < 4; ++r) {
                float sqd = rsq[fm][r] + csq[fn] - 2.0f * acc[fm][fn][r];
                float d = sqrtf(fmaxf(sqd, 0.0f));
                rp[fm][r] += d;
                if (offdiag) cp[fn] += d;
            }

    #pragma unroll
    for (int fm = 0; fm < 4; ++fm)
        #pragma unroll
        for (int r = 0; r < 4; ++r) {
            float v = rp[fm][r];
            v += __shfl_xor(v, 1, 64);
            v += __shfl_xor(v, 2, 64);
            v += __shfl_xor(v, 4, 64);
            v += __shfl_xor(v, 8, 64);
            if (l15 == 0)
                atomicAdd(&denom[row0 + wm * 64 + fm * 16 + lk * 4 + r], v);
        }
    if (offdiag) {
        #pragma unroll
        for (int fn = 0; fn < 4; ++fn) {
            float v = cp[fn];
            v += __shfl_xor(v, 16, 64);
            v += __shfl_xor(v, 32, 64);
            if (lane < 16)
                atomicAdd(&denom[col0 + wn * 64 + fn * 16 + l15], v);
        }
    }
}

// ---------------------------------------------------------------------------
__global__ void inv_kernel(float* __restrict__ denom) {
    int i = blockIdx.x * 256 + threadIdx.x;
    if (i < NN) denom[i] = 1.0f / denom[i];
}

// ---------------------------------------------------------------------------
// Pass 2: recompute d (bit-identical K-loop), scale by inv, write direct
// tile + LDS-transposed mirror tile.  No atomics.
// ---------------------------------------------------------------------------
__launch_bounds__(256, 2)
__global__ void write_kernel(const unsigned short* __restrict__ hi,
                             const unsigned short* __restrict__ lo,
                             const float* __restrict__ sq,
                             const float* __restrict__ inv,
                             float* __restrict__ out) {
    __shared__ __align__(16) unsigned short lds[4 * 128 * 64];  // 64 KB
    unsigned short* ldsAhi = lds;
    unsigned short* ldsAlo = lds + 8192;
    unsigned short* ldsBhi = lds + 16384;
    unsigned short* ldsBlo = lds + 24576;

    DIST_PROLOG()

    float rinv[4][4];
    #pragma unroll
    for (int fm = 0; fm < 4; ++fm)
        #pragma unroll
        for (int r = 0; r < 4; ++r)
            rinv[fm][r] = inv[row0 + wm * 64 + fm * 16 + lk * 4 + r];

    DIST_KLOOP()

    float* ldsT = reinterpret_cast<float*>(lds);  // reuse staging LDS

    #pragma unroll
    for (int fm = 0; fm < 4; ++fm)
        #pragma unroll
        for (int fn = 0; fn < 4; ++fn)
            #pragma unroll
            for (int r = 0; r < 4; ++r) {
                float sqd = rsq[fm][r] + csq[fn] - 2.0f * acc[fm][fn][r];
                float d = sqrtf(fmaxf(sqd, 0.0f));
                int lr = wm * 64 + fm * 16 + lk * 4 + r;   // local row
                int lc = wn * 64 + fn * 16 + l15;          // local col
                out[(size_t)(row0 + lr) * NN + col0 + lc] = d * rinv[fm][r];
                if (offdiag)
                    ldsT[lc * 128 + (lr ^ ((lc & 31) ^ ((lc & 4) << 2)))] = d;
            }

    if (offdiag) {
        __syncthreads();
        #pragma unroll
        for (int it = 0; it < 64; ++it) {
            int idx = it * 256 + tid;
            int c  = idx >> 7;
            int r_ = idx & 127;
            float d = ldsT[c * 128 + (r_ ^ ((c & 31) ^ ((c & 4) << 2)))];
            out[(size_t)(col0 + c) * NN + row0 + r_] = d * inv[col0 + c];
        }
    }
}

extern "C" void kernel_launch(void* const* d_in, const int* in_sizes, int n_in,
                              void* d_out, int out_size, void* d_ws, size_t ws_size,
                              hipStream_t stream) {
    const float* x = (const float*)d_in[0];
    float* out = (float*)d_out;
    char* ws = (char*)d_ws;
    unsigned short* hi = (unsigned short*)ws;                          // 4 MB
    unsigned short* lo = (unsigned short*)(ws + (size_t)NN * DD * 2);  // 4 MB
    float* sq    = (float*)(ws + (size_t)NN * DD * 4);                 // 32 KB
    float* denom = (float*)(ws + (size_t)NN * DD * 4 + NN * 4);        // 32 KB

    prep_kernel<<<NN, 256, 0, stream>>>(x, hi, lo, sq, denom);
    sum_kernel<<<2080, 256, 0, stream>>>(hi, lo, sq, denom);
    inv_kernel<<<32, 256, 0, stream>>>(denom);
    write_kernel<<<2080, 256, 0, stream>>>(hi, lo, sq, denom, out);
}